// Round 1
// baseline (1188.472 us; speedup 1.0000x reference)
//
#include <hip/hip_runtime.h>

#define F_IN 500
#define HH 32
#define DD 64
#define LN_EPS 1e-6f

// ---------------------------------------------------------------------------
// Encoder: h = L2norm( relu(LN(x@W1+b1))@W2 + b2 )
// block = 256 threads (4 waves); each wave handles 8 rows (block = 32 rows).
// lane = j + 32*p : half-wave p owns rows [base+4p, base+4p+4), j = channel.
// ---------------------------------------------------------------------------
__global__ __launch_bounds__(256, 2)
void encoder_k(const float* __restrict__ x,
               const float* __restrict__ W1, const float* __restrict__ b1,
               const float* __restrict__ gamma, const float* __restrict__ beta,
               const float* __restrict__ W2, const float* __restrict__ b2,
               float* __restrict__ h0, int N)
{
    __shared__ float W1s[F_IN * HH];                      // 64000 B
    __shared__ float W2s[HH * DD];                        // 8192 B
    __shared__ __attribute__((aligned(16))) float hrs[4][8][HH]; // 4096 B

    const int tid = threadIdx.x;
    for (int i = tid; i < F_IN * HH; i += 256) W1s[i] = W1[i];
    for (int i = tid; i < HH * DD;  i += 256) W2s[i] = W2[i];
    __syncthreads();

    const int wave = tid >> 6;
    const int lane = tid & 63;
    const int j = lane & 31;
    const int p = lane >> 5;
    const int waveRow0 = blockIdx.x * 32 + wave * 8;      // 8 rows for this wave
    const int rowBase  = waveRow0 + p * 4;                // 4 rows for this half

    const float b1j = b1[j];
    const float gj  = gamma[j];
    const float bj  = beta[j];

    float acc0 = b1j, acc1 = b1j, acc2 = b1j, acc3 = b1j;

    const float* xp0 = x + (size_t)min(rowBase + 0, N - 1) * F_IN;
    const float* xp1 = x + (size_t)min(rowBase + 1, N - 1) * F_IN;
    const float* xp2 = x + (size_t)min(rowBase + 2, N - 1) * F_IN;
    const float* xp3 = x + (size_t)min(rowBase + 3, N - 1) * F_IN;

    #pragma unroll 2
    for (int k = 0; k < F_IN; k += 4) {
        float4 x0 = *(const float4*)(xp0 + k);
        float4 x1 = *(const float4*)(xp1 + k);
        float4 x2 = *(const float4*)(xp2 + k);
        float4 x3 = *(const float4*)(xp3 + k);
        float w0 = W1s[(k + 0) * HH + j];
        float w1 = W1s[(k + 1) * HH + j];
        float w2 = W1s[(k + 2) * HH + j];
        float w3 = W1s[(k + 3) * HH + j];
        acc0 = fmaf(x0.x, w0, acc0); acc0 = fmaf(x0.y, w1, acc0);
        acc0 = fmaf(x0.z, w2, acc0); acc0 = fmaf(x0.w, w3, acc0);
        acc1 = fmaf(x1.x, w0, acc1); acc1 = fmaf(x1.y, w1, acc1);
        acc1 = fmaf(x1.z, w2, acc1); acc1 = fmaf(x1.w, w3, acc1);
        acc2 = fmaf(x2.x, w0, acc2); acc2 = fmaf(x2.y, w1, acc2);
        acc2 = fmaf(x2.z, w2, acc2); acc2 = fmaf(x2.w, w3, acc2);
        acc3 = fmaf(x3.x, w0, acc3); acc3 = fmaf(x3.y, w1, acc3);
        acc3 = fmaf(x3.z, w2, acc3); acc3 = fmaf(x3.w, w3, acc3);
    }

    // LayerNorm over 32 channels (reduction within 32-lane half via xor masks<32)
    float accs[4] = {acc0, acc1, acc2, acc3};
    #pragma unroll
    for (int r = 0; r < 4; ++r) {
        float h = accs[r];
        float s = h;
        #pragma unroll
        for (int m = 1; m < 32; m <<= 1) s += __shfl_xor(s, m, 64);
        float mu = s * (1.0f / 32.0f);
        float d0 = h - mu;
        float vv = d0 * d0;
        #pragma unroll
        for (int m = 1; m < 32; m <<= 1) vv += __shfl_xor(vv, m, 64);
        vv *= (1.0f / 32.0f);
        float hn = d0 * rsqrtf(vv + LN_EPS);
        hn = fmaf(hn, gj, bj);
        hn = fmaxf(hn, 0.0f);                    // relu
        hrs[wave][p * 4 + r][j] = hn;
    }
    __syncthreads();

    // GEMM2 [8 rows x 32] @ [32 x 64], then row L2-normalize.
    const int d = lane;                          // output dim 0..63
    const float b2d = b2[d];
    #pragma unroll 1
    for (int rl = 0; rl < 8; ++rl) {
        int row = waveRow0 + rl;
        float o = b2d;
        #pragma unroll
        for (int jj = 0; jj < HH; jj += 4) {
            float4 hv = *(const float4*)&hrs[wave][rl][jj];
            o = fmaf(hv.x, W2s[(jj + 0) * DD + d], o);
            o = fmaf(hv.y, W2s[(jj + 1) * DD + d], o);
            o = fmaf(hv.z, W2s[(jj + 2) * DD + d], o);
            o = fmaf(hv.w, W2s[(jj + 3) * DD + d], o);
        }
        float ss = o * o;
        #pragma unroll
        for (int m = 1; m < 64; m <<= 1) ss += __shfl_xor(ss, m, 64);
        float nrm = sqrtf(ss);
        float scale = 1.0f / fmaxf(nrm, 1e-12f);
        if (row < N) h0[(size_t)row * DD + d] = o * scale;
    }
}

// ---------------------------------------------------------------------------
// Graph plumbing: degree count -> per-block scan for segment bases -> CSR fill
// ---------------------------------------------------------------------------
__global__ void zero_k(int* __restrict__ p, int n)
{
    int i = blockIdx.x * blockDim.x + threadIdx.x;
    int stride = gridDim.x * blockDim.x;
    for (; i < n; i += stride) p[i] = 0;
}

__global__ void count_k(const int* __restrict__ col, int M, int* __restrict__ cnt)
{
    int i = blockIdx.x * blockDim.x + threadIdx.x;
    int stride = gridDim.x * blockDim.x;
    for (; i < M; i += stride) atomicAdd(&cnt[col[i]], 1);
}

// start[v] = segment base (arbitrary cross-block order, deterministic output),
// dinv[v] = deg>0 ? rsqrt(deg) : 0
__global__ __launch_bounds__(256)
void scan_dinv_k(const int* __restrict__ cnt, int* __restrict__ start,
                 float* __restrict__ dinv, int* __restrict__ gctr, int N)
{
    __shared__ int sd[256];
    __shared__ int sbase;
    int t = threadIdx.x;
    int v = blockIdx.x * 256 + t;
    int c = (v < N) ? cnt[v] : 0;
    sd[t] = c;
    __syncthreads();
    #pragma unroll
    for (int off = 1; off < 256; off <<= 1) {
        int tmp = (t >= off) ? sd[t - off] : 0;
        __syncthreads();
        sd[t] += tmp;
        __syncthreads();
    }
    int incl = sd[t];
    if (t == 255) sbase = atomicAdd(gctr, sd[255]);
    __syncthreads();
    if (v < N) {
        start[v] = sbase + incl - c;
        dinv[v]  = (c > 0) ? rsqrtf((float)c) : 0.0f;
    }
}

__global__ void fill_k(const int* __restrict__ row, const int* __restrict__ col, int M,
                       const int* __restrict__ start, int* __restrict__ cursor,
                       const float* __restrict__ dinv,
                       int* __restrict__ csr_src, float* __restrict__ csr_w)
{
    int i = blockIdx.x * blockDim.x + threadIdx.x;
    int stride = gridDim.x * blockDim.x;
    for (; i < M; i += stride) {
        int r = row[i];
        int c = col[i];
        int pos = start[c] + atomicAdd(&cursor[c], 1);
        csr_src[pos] = r;
        csr_w[pos]   = dinv[r] * dinv[c];
    }
}

// ---------------------------------------------------------------------------
// Propagation: one wave per node, lane = feature dim. Gather-reduce, no atomics.
// ---------------------------------------------------------------------------
__global__ __launch_bounds__(256)
void prop_k(const float* __restrict__ hin, float* __restrict__ hout,
            const int* __restrict__ start, const int* __restrict__ cnt,
            const int* __restrict__ csr_src, const float* __restrict__ csr_w, int N)
{
    int v = blockIdx.x * 4 + (threadIdx.x >> 6);
    int lane = threadIdx.x & 63;
    if (v >= N) return;
    int s = start[v];
    int e = s + cnt[v];
    float acc = 0.0f;
    int i = s;
    for (; i + 1 < e; i += 2) {
        int   r0 = csr_src[i],   r1 = csr_src[i + 1];
        float w0 = csr_w[i],     w1 = csr_w[i + 1];
        acc = fmaf(w0, hin[(size_t)r0 * DD + lane], acc);
        acc = fmaf(w1, hin[(size_t)r1 * DD + lane], acc);
    }
    if (i < e) {
        int r = csr_src[i];
        acc = fmaf(csr_w[i], hin[(size_t)r * DD + lane], acc);
    }
    hout[(size_t)v * DD + lane] = acc;
}

// ---------------------------------------------------------------------------
extern "C" void kernel_launch(void* const* d_in, const int* in_sizes, int n_in,
                              void* d_out, int out_size, void* d_ws, size_t ws_size,
                              hipStream_t stream)
{
    const float* x     = (const float*)d_in[0];
    const int*   ei    = (const int*)  d_in[1];
    const float* W1    = (const float*)d_in[2];
    const float* b1    = (const float*)d_in[3];
    const float* gamma = (const float*)d_in[4];
    const float* beta  = (const float*)d_in[5];
    const float* W2    = (const float*)d_in[6];
    const float* b2    = (const float*)d_in[7];
    float* out = (float*)d_out;

    const int N = in_sizes[0] / F_IN;       // 100000
    const int M = in_sizes[1] / 2;          // 3300000
    const int* erow = ei;
    const int* ecol = ei + M;

    // workspace layout
    char* w = (char*)d_ws;
    int*   cnt     = (int*)w;   w += (size_t)N * 4;
    int*   cursor  = (int*)w;   w += (size_t)N * 4;
    int*   gctr    = (int*)w;   w += 16;                 // zeroed with cnt/cursor
    int*   startv  = (int*)w;   w += (size_t)N * 4;
    float* dinv    = (float*)w; w += (size_t)N * 4;
    int*   csr_src = (int*)w;   w += (size_t)M * 4;
    float* csr_w   = (float*)w; /* w += (size_t)M * 4; */

    // 1. zero cnt, cursor, gctr (contiguous 2N+4 ints)
    zero_k<<<512, 256, 0, stream>>>((int*)d_ws, 2 * N + 4);

    // 2. encoder -> out[0 .. N*64)
    encoder_k<<<(N + 31) / 32, 256, 0, stream>>>(x, W1, b1, gamma, beta, W2, b2, out, N);

    // 3. degree count over col
    count_k<<<2048, 256, 0, stream>>>(ecol, M, cnt);

    // 4. segment bases + dinv
    scan_dinv_k<<<(N + 255) / 256, 256, 0, stream>>>(cnt, startv, dinv, gctr, N);

    // 5. CSR fill (group edges by target col)
    fill_k<<<2048, 256, 0, stream>>>(erow, ecol, M, startv, cursor, dinv, csr_src, csr_w);

    // 6. two propagation steps
    float* h0 = out;
    float* h1 = out + (size_t)N * DD;
    float* h2 = out + 2 * (size_t)N * DD;
    prop_k<<<(N + 3) / 4, 256, 0, stream>>>(h0, h1, startv, cnt, csr_src, csr_w, N);
    prop_k<<<(N + 3) / 4, 256, 0, stream>>>(h1, h2, startv, cnt, csr_src, csr_w, N);
}

// Round 2
// 756.835 us; speedup vs baseline: 1.5703x; 1.5703x over previous
//
#include <hip/hip_runtime.h>

#define F_IN 500
#define HH 32
#define DD 64
#define LN_EPS 1e-6f
#define RB 256          // rows per encoder block (1 thread : 1 row)
#define NCHUNK 16       // ceil(500 / 32): 15 full chunks of 32 k + tail of 20

typedef float4 f4;

__device__ __forceinline__ void gload_lds16(const void* g, void* l) {
    __builtin_amdgcn_global_load_lds((const __attribute__((address_space(1))) void*)g,
                                     (__attribute__((address_space(3))) void*)l, 16, 0, 0);
}

// ---------------------------------------------------------------------------
// Encoder: thread t owns row row0+t. x staged to LDS (coalesced, dbuf,
// source-pre-swizzled so compute ds_read_b128 is conflict-free). W1 read with
// wave-uniform indices -> s_load (scalar pipe). LN/GEMM2/L2norm per-thread.
// LDS: xs 64 KB + W2s 8 KB -> 2 blocks/CU.
// ---------------------------------------------------------------------------
__global__ __launch_bounds__(256, 2)
void encoder_k(const float* __restrict__ x,
               const float* __restrict__ W1, const float* __restrict__ b1,
               const float* __restrict__ gamma, const float* __restrict__ beta,
               const float* __restrict__ W2, const float* __restrict__ b2,
               float* __restrict__ h0, int N)
{
    __shared__ f4 xs[2][RB * 8];        // 2 x 32 KB; slot n = r*8+u holds quad (u^(r&7)) of row r
    __shared__ float W2s[HH * DD];      // 8 KB

    const int t = threadIdx.x;
    const int w = t >> 6;               // wave id (uniform per wave)
    const int l = t & 63;
    const int row0 = blockIdx.x * RB;

    for (int i = t; i < HH * DD; i += 256) W2s[i] = W2[i];

    float acc[HH];
    #pragma unroll
    for (int j = 0; j < HH; ++j) acc[j] = b1[j];   // uniform s_loads

    // ---- staging macro: 8 global_load_lds(16B) per thread per chunk ----
    #define STAGE(c_, nb_) do {                                              \
        const int k0_ = (c_) * 32;                                           \
        _Pragma("unroll")                                                    \
        for (int i_ = 0; i_ < 8; ++i_) {                                     \
            int n_ = (i_ * 4 + w) * 64 + l;                                  \
            int r_ = n_ >> 3, u_ = n_ & 7;                                   \
            int g_ = u_ ^ (r_ & 7);                                          \
            int k_ = k0_ + 4 * g_;                                           \
            if (k_ >= F_IN) k_ = 0;            /* dummy, never read */       \
            int row_ = row0 + r_; if (row_ >= N) row_ = N - 1;               \
            const float* src_ = x + (size_t)row_ * F_IN + k_;                \
            gload_lds16((const void*)src_, (void*)&xs[nb_][(i_ * 4 + w) * 64]); \
        }                                                                    \
    } while (0)

    STAGE(0, 0);
    __syncthreads();                    // drains vmcnt(0): buf0 + W2s ready

    const int sw = t & 7;
    for (int c = 0; c < NCHUNK; ++c) {
        const int cb = c & 1;
        if (c + 1 < NCHUNK) STAGE(c + 1, cb ^ 1);
        const int nq = (c == NCHUNK - 1) ? 5 : 8;   // tail: k 480..499
        const f4* xb = &xs[cb][t * 8];
        const int k0 = c * 32;
        #pragma unroll
        for (int q = 0; q < 8; ++q) {
            if (q < nq) {
                f4 xv = xb[q ^ sw];
                #pragma unroll
                for (int dk = 0; dk < 4; ++dk) {
                    float xk = ((const float*)&xv)[dk];
                    const float* wr = W1 + (size_t)(k0 + 4 * q + dk) * HH;  // uniform
                    #pragma unroll
                    for (int j = 0; j < HH; ++j)
                        acc[j] = fmaf(xk, wr[j], acc[j]);     // VGPR x SGPR
                }
            }
        }
        __syncthreads();                // own vmcnt drained + all waves done with cb
    }
    #undef STAGE

    // ---- LayerNorm (fully per-thread) + relu ----
    float s = 0.f;
    #pragma unroll
    for (int j = 0; j < HH; ++j) s += acc[j];
    float mu = s * (1.0f / 32.0f);
    float var = 0.f;
    #pragma unroll
    for (int j = 0; j < HH; ++j) { float d = acc[j] - mu; var = fmaf(d, d, var); }
    float is = rsqrtf(var * (1.0f / 32.0f) + LN_EPS);
    #pragma unroll
    for (int j = 0; j < HH; ++j) {
        float hn = (acc[j] - mu) * is;
        hn = fmaf(hn, gamma[j], beta[j]);          // uniform s_loads
        acc[j] = fmaxf(hn, 0.0f);
    }

    // ---- GEMM2: o[64] = relu(h) @ W2 + b2 (W2 broadcast from LDS) ----
    float o[DD];
    #pragma unroll
    for (int d = 0; d < DD; ++d) o[d] = b2[d];     // uniform s_loads
    #pragma unroll
    for (int j = 0; j < HH; ++j) {
        float hj = acc[j];
        #pragma unroll
        for (int dq = 0; dq < DD / 4; ++dq) {
            f4 wv = *(const f4*)&W2s[j * DD + dq * 4];   // broadcast b128
            o[dq * 4 + 0] = fmaf(hj, wv.x, o[dq * 4 + 0]);
            o[dq * 4 + 1] = fmaf(hj, wv.y, o[dq * 4 + 1]);
            o[dq * 4 + 2] = fmaf(hj, wv.z, o[dq * 4 + 2]);
            o[dq * 4 + 3] = fmaf(hj, wv.w, o[dq * 4 + 3]);
        }
    }

    // ---- row L2 normalize ----
    float ss = 0.f;
    #pragma unroll
    for (int d = 0; d < DD; ++d) ss = fmaf(o[d], o[d], ss);
    float sc = 1.0f / fmaxf(sqrtf(ss), 1e-12f);

    // ---- transpose through freed xs -> coalesced global stores ----
    __syncthreads();
    f4* ot = (f4*)&xs[0][0];            // [256 rows][16 quads]
    #pragma unroll
    for (int dq = 0; dq < 16; ++dq) {
        f4 v4;
        v4.x = o[dq * 4 + 0] * sc; v4.y = o[dq * 4 + 1] * sc;
        v4.z = o[dq * 4 + 2] * sc; v4.w = o[dq * 4 + 3] * sc;
        ot[t * 16 + dq] = v4;
    }
    __syncthreads();
    f4* out4 = (f4*)h0;
    #pragma unroll
    for (int i = 0; i < 16; ++i) {
        int idx = i * 256 + t;
        int r = idx >> 4, dq = idx & 15;
        int row = row0 + r;
        if (row < N) out4[(size_t)row * 16 + dq] = ot[idx];
    }
}

// ---------------------------------------------------------------------------
// Graph plumbing: degree count -> per-block scan for segment bases -> CSR fill
// ---------------------------------------------------------------------------
__global__ void zero_k(int* __restrict__ p, int n)
{
    int i = blockIdx.x * blockDim.x + threadIdx.x;
    int stride = gridDim.x * blockDim.x;
    for (; i < n; i += stride) p[i] = 0;
}

__global__ void count_k(const int* __restrict__ col, int M, int* __restrict__ cnt)
{
    int i = blockIdx.x * blockDim.x + threadIdx.x;
    int stride = gridDim.x * blockDim.x;
    for (; i < M; i += stride) atomicAdd(&cnt[col[i]], 1);
}

__global__ __launch_bounds__(256)
void scan_dinv_k(const int* __restrict__ cnt, int* __restrict__ start,
                 float* __restrict__ dinv, int* __restrict__ gctr, int N)
{
    __shared__ int sd[256];
    __shared__ int sbase;
    int t = threadIdx.x;
    int v = blockIdx.x * 256 + t;
    int c = (v < N) ? cnt[v] : 0;
    sd[t] = c;
    __syncthreads();
    #pragma unroll
    for (int off = 1; off < 256; off <<= 1) {
        int tmp = (t >= off) ? sd[t - off] : 0;
        __syncthreads();
        sd[t] += tmp;
        __syncthreads();
    }
    int incl = sd[t];
    if (t == 255) sbase = atomicAdd(gctr, sd[255]);
    __syncthreads();
    if (v < N) {
        start[v] = sbase + incl - c;
        dinv[v]  = (c > 0) ? rsqrtf((float)c) : 0.0f;
    }
}

__global__ void fill_k(const int* __restrict__ row, const int* __restrict__ col, int M,
                       const int* __restrict__ start, int* __restrict__ cursor,
                       const float* __restrict__ dinv,
                       int* __restrict__ csr_src, float* __restrict__ csr_w)
{
    int i = blockIdx.x * blockDim.x + threadIdx.x;
    int stride = gridDim.x * blockDim.x;
    for (; i < M; i += stride) {
        int r = row[i];
        int c = col[i];
        int pos = start[c] + atomicAdd(&cursor[c], 1);
        csr_src[pos] = r;
        csr_w[pos]   = dinv[r] * dinv[c];
    }
}

// ---------------------------------------------------------------------------
// Propagation: one wave per node, lane = feature dim. Gather-reduce, no atomics.
// csr indices are wave-uniform -> scalar loads; h row reads are coalesced 256B.
// ---------------------------------------------------------------------------
__global__ __launch_bounds__(256)
void prop_k(const float* __restrict__ hin, float* __restrict__ hout,
            const int* __restrict__ start, const int* __restrict__ cnt,
            const int* __restrict__ csr_src, const float* __restrict__ csr_w, int N)
{
    int v = blockIdx.x * 4 + (threadIdx.x >> 6);
    int lane = threadIdx.x & 63;
    if (v >= N) return;
    int s = start[v];
    int e = s + cnt[v];
    float acc = 0.0f;
    int i = s;
    for (; i + 3 < e; i += 4) {
        int   r0 = csr_src[i],     r1 = csr_src[i + 1];
        int   r2 = csr_src[i + 2], r3 = csr_src[i + 3];
        float w0 = csr_w[i],     w1 = csr_w[i + 1];
        float w2 = csr_w[i + 2], w3 = csr_w[i + 3];
        float v0 = hin[(size_t)r0 * DD + lane];
        float v1 = hin[(size_t)r1 * DD + lane];
        float v2 = hin[(size_t)r2 * DD + lane];
        float v3 = hin[(size_t)r3 * DD + lane];
        acc = fmaf(w0, v0, acc); acc = fmaf(w1, v1, acc);
        acc = fmaf(w2, v2, acc); acc = fmaf(w3, v3, acc);
    }
    for (; i < e; ++i) {
        int r = csr_src[i];
        acc = fmaf(csr_w[i], hin[(size_t)r * DD + lane], acc);
    }
    hout[(size_t)v * DD + lane] = acc;
}

// ---------------------------------------------------------------------------
extern "C" void kernel_launch(void* const* d_in, const int* in_sizes, int n_in,
                              void* d_out, int out_size, void* d_ws, size_t ws_size,
                              hipStream_t stream)
{
    const float* x     = (const float*)d_in[0];
    const int*   ei    = (const int*)  d_in[1];
    const float* W1    = (const float*)d_in[2];
    const float* b1    = (const float*)d_in[3];
    const float* gamma = (const float*)d_in[4];
    const float* beta  = (const float*)d_in[5];
    const float* W2    = (const float*)d_in[6];
    const float* b2    = (const float*)d_in[7];
    float* out = (float*)d_out;

    const int N = in_sizes[0] / F_IN;       // 100000
    const int M = in_sizes[1] / 2;          // 3300000
    const int* erow = ei;
    const int* ecol = ei + M;

    // workspace layout
    char* w = (char*)d_ws;
    int*   cnt     = (int*)w;   w += (size_t)N * 4;
    int*   cursor  = (int*)w;   w += (size_t)N * 4;
    int*   gctr    = (int*)w;   w += 16;
    int*   startv  = (int*)w;   w += (size_t)N * 4;
    float* dinv    = (float*)w; w += (size_t)N * 4;
    int*   csr_src = (int*)w;   w += (size_t)M * 4;
    float* csr_w   = (float*)w;

    zero_k<<<512, 256, 0, stream>>>((int*)d_ws, 2 * N + 4);

    encoder_k<<<(N + RB - 1) / RB, 256, 0, stream>>>(x, W1, b1, gamma, beta, W2, b2, out, N);

    count_k<<<2048, 256, 0, stream>>>(ecol, M, cnt);
    scan_dinv_k<<<(N + 255) / 256, 256, 0, stream>>>(cnt, startv, dinv, gctr, N);
    fill_k<<<2048, 256, 0, stream>>>(erow, ecol, M, startv, cursor, dinv, csr_src, csr_w);

    float* h0 = out;
    float* h1 = out + (size_t)N * DD;
    float* h2 = out + 2 * (size_t)N * DD;
    prop_k<<<(N + 3) / 4, 256, 0, stream>>>(h0, h1, startv, cnt, csr_src, csr_w, N);
    prop_k<<<(N + 3) / 4, 256, 0, stream>>>(h1, h2, startv, cnt, csr_src, csr_w, N);
}

// Round 3
// 729.501 us; speedup vs baseline: 1.6292x; 1.0375x over previous
//
#include <hip/hip_runtime.h>

#define F_IN 500
#define HH 32
#define DD 64
#define LN_EPS 1e-6f
#define RB 256          // rows per encoder block (1 thread : 1 row)
#define NCHUNK 16       // ceil(500 / 32)
#define NPART 8         // XCD partitions for count/fill scatter locality

typedef float4 f4;

__device__ __forceinline__ void gload_lds16(const void* g, void* l) {
    __builtin_amdgcn_global_load_lds((const __attribute__((address_space(1))) void*)g,
                                     (__attribute__((address_space(3))) void*)l, 16, 0, 0);
}

// ---------------------------------------------------------------------------
// Encoder: thread t owns row row0+t. x staged to LDS (coalesced, dbuf,
// source-pre-swizzled so compute ds_read_b128 is conflict-free). W1 read with
// wave-uniform indices -> s_load (scalar pipe). LN/GEMM2/L2norm per-thread.
// ---------------------------------------------------------------------------
__global__ __launch_bounds__(256, 2)
void encoder_k(const float* __restrict__ x,
               const float* __restrict__ W1, const float* __restrict__ b1,
               const float* __restrict__ gamma, const float* __restrict__ beta,
               const float* __restrict__ W2, const float* __restrict__ b2,
               float* __restrict__ h0, int N)
{
    __shared__ f4 xs[2][RB * 8];        // 2 x 32 KB
    __shared__ float W2s[HH * DD];      // 8 KB

    const int t = threadIdx.x;
    const int w = t >> 6;
    const int l = t & 63;
    const int row0 = blockIdx.x * RB;

    for (int i = t; i < HH * DD; i += 256) W2s[i] = W2[i];

    float acc[HH];
    #pragma unroll
    for (int j = 0; j < HH; ++j) acc[j] = b1[j];

    #define STAGE(c_, nb_) do {                                              \
        const int k0_ = (c_) * 32;                                           \
        _Pragma("unroll")                                                    \
        for (int i_ = 0; i_ < 8; ++i_) {                                     \
            int n_ = (i_ * 4 + w) * 64 + l;                                  \
            int r_ = n_ >> 3, u_ = n_ & 7;                                   \
            int g_ = u_ ^ (r_ & 7);                                          \
            int k_ = k0_ + 4 * g_;                                           \
            if (k_ >= F_IN) k_ = 0;                                          \
            int row_ = row0 + r_; if (row_ >= N) row_ = N - 1;               \
            const float* src_ = x + (size_t)row_ * F_IN + k_;                \
            gload_lds16((const void*)src_, (void*)&xs[nb_][(i_ * 4 + w) * 64]); \
        }                                                                    \
    } while (0)

    STAGE(0, 0);
    __syncthreads();

    const int sw = t & 7;
    for (int c = 0; c < NCHUNK; ++c) {
        const int cb = c & 1;
        if (c + 1 < NCHUNK) STAGE(c + 1, cb ^ 1);
        const int nq = (c == NCHUNK - 1) ? 5 : 8;
        const f4* xb = &xs[cb][t * 8];
        const int k0 = c * 32;
        #pragma unroll
        for (int q = 0; q < 8; ++q) {
            if (q < nq) {
                f4 xv = xb[q ^ sw];
                #pragma unroll
                for (int dk = 0; dk < 4; ++dk) {
                    float xk = ((const float*)&xv)[dk];
                    const float* wr = W1 + (size_t)(k0 + 4 * q + dk) * HH;
                    #pragma unroll
                    for (int j = 0; j < HH; ++j)
                        acc[j] = fmaf(xk, wr[j], acc[j]);
                }
            }
        }
        __syncthreads();
    }
    #undef STAGE

    // LayerNorm + relu (per-thread)
    float s = 0.f;
    #pragma unroll
    for (int j = 0; j < HH; ++j) s += acc[j];
    float mu = s * (1.0f / 32.0f);
    float var = 0.f;
    #pragma unroll
    for (int j = 0; j < HH; ++j) { float d = acc[j] - mu; var = fmaf(d, d, var); }
    float is = rsqrtf(var * (1.0f / 32.0f) + LN_EPS);
    #pragma unroll
    for (int j = 0; j < HH; ++j) {
        float hn = (acc[j] - mu) * is;
        hn = fmaf(hn, gamma[j], beta[j]);
        acc[j] = fmaxf(hn, 0.0f);
    }

    // GEMM2 + L2 normalize
    float o[DD];
    #pragma unroll
    for (int d = 0; d < DD; ++d) o[d] = b2[d];
    #pragma unroll
    for (int j = 0; j < HH; ++j) {
        float hj = acc[j];
        #pragma unroll
        for (int dq = 0; dq < DD / 4; ++dq) {
            f4 wv = *(const f4*)&W2s[j * DD + dq * 4];
            o[dq * 4 + 0] = fmaf(hj, wv.x, o[dq * 4 + 0]);
            o[dq * 4 + 1] = fmaf(hj, wv.y, o[dq * 4 + 1]);
            o[dq * 4 + 2] = fmaf(hj, wv.z, o[dq * 4 + 2]);
            o[dq * 4 + 3] = fmaf(hj, wv.w, o[dq * 4 + 3]);
        }
    }
    float ss = 0.f;
    #pragma unroll
    for (int d = 0; d < DD; ++d) ss = fmaf(o[d], o[d], ss);
    float sc = 1.0f / fmaxf(sqrtf(ss), 1e-12f);

    // transpose through freed xs -> coalesced stores
    __syncthreads();
    f4* ot = (f4*)&xs[0][0];
    #pragma unroll
    for (int dq = 0; dq < 16; ++dq) {
        f4 v4;
        v4.x = o[dq * 4 + 0] * sc; v4.y = o[dq * 4 + 1] * sc;
        v4.z = o[dq * 4 + 2] * sc; v4.w = o[dq * 4 + 3] * sc;
        ot[t * 16 + dq] = v4;
    }
    __syncthreads();
    f4* out4 = (f4*)h0;
    #pragma unroll
    for (int i = 0; i < 16; ++i) {
        int idx = i * 256 + t;
        int r = idx >> 4, dq = idx & 15;
        int row = row0 + r;
        if (row < N) out4[(size_t)row * 16 + dq] = ot[idx];
    }
}

// ---------------------------------------------------------------------------
// Graph plumbing, XCD-partitioned: cohort p = blockIdx&7 handles target nodes
// [pN/8,(p+1)N/8). Scattered cnt/cursor/csr writes land in ~1.7MB per-XCD
// ranges -> L2-resident. Cohort grid-strides over the whole edge list.
// ---------------------------------------------------------------------------
__global__ void zero_k(int* __restrict__ p, int n)
{
    int i = blockIdx.x * blockDim.x + threadIdx.x;
    int stride = gridDim.x * blockDim.x;
    for (; i < n; i += stride) p[i] = 0;
}

__global__ __launch_bounds__(256)
void count_part_k(const int* __restrict__ col, int M, int* __restrict__ cnt, int N)
{
    const int part  = blockIdx.x & (NPART - 1);
    const int crank = blockIdx.x >> 3;                 // rank within cohort
    const int cblocks = gridDim.x >> 3;
    const int nlo = (int)((long long)part * N / NPART);
    const int nhi = (int)((long long)(part + 1) * N / NPART);
    const int stride = cblocks * 256;
    for (int i = crank * 256 + threadIdx.x; i < M; i += stride) {
        int c = col[i];
        if (c >= nlo && c < nhi) atomicAdd(&cnt[c], 1);
    }
}

__global__ __launch_bounds__(256)
void scan_dinv_k(const int* __restrict__ cnt, int* __restrict__ start,
                 float* __restrict__ dinv, int* __restrict__ gctr, int N)
{
    __shared__ int sd[256];
    __shared__ int sbase;
    int t = threadIdx.x;
    int v = blockIdx.x * 256 + t;
    int c = (v < N) ? cnt[v] : 0;
    sd[t] = c;
    __syncthreads();
    #pragma unroll
    for (int off = 1; off < 256; off <<= 1) {
        int tmp = (t >= off) ? sd[t - off] : 0;
        __syncthreads();
        sd[t] += tmp;
        __syncthreads();
    }
    int incl = sd[t];
    if (t == 255) sbase = atomicAdd(gctr, sd[255]);
    __syncthreads();
    if (v < N) {
        start[v] = sbase + incl - c;
        dinv[v]  = (c > 0) ? rsqrtf((float)c) : 0.0f;
    }
}

__global__ __launch_bounds__(256)
void fill_part_k(const int* __restrict__ row, const int* __restrict__ col, int M,
                 const int* __restrict__ start, int* __restrict__ cursor,
                 int* __restrict__ csr_src, int N)
{
    const int part  = blockIdx.x & (NPART - 1);
    const int crank = blockIdx.x >> 3;
    const int cblocks = gridDim.x >> 3;
    const int nlo = (int)((long long)part * N / NPART);
    const int nhi = (int)((long long)(part + 1) * N / NPART);
    const int stride = cblocks * 256;
    for (int i = crank * 256 + threadIdx.x; i < M; i += stride) {
        int c = col[i];
        if (c >= nlo && c < nhi) {
            int r = row[i];
            int pos = start[c] + atomicAdd(&cursor[c], 1);
            csr_src[pos] = r;
        }
    }
}

// ---------------------------------------------------------------------------
// Propagation: wave per node, lane = feature dim. Weight computed on the fly:
// hout[v] = dinv[v] * sum_r dinv[r]*hin[r]  (dinv is 400KB, L2-resident).
// ---------------------------------------------------------------------------
__global__ __launch_bounds__(256)
void prop_k(const float* __restrict__ hin, float* __restrict__ hout,
            const int* __restrict__ start, const int* __restrict__ cnt,
            const int* __restrict__ csr_src, const float* __restrict__ dinv, int N)
{
    int v = blockIdx.x * 4 + (threadIdx.x >> 6);
    int lane = threadIdx.x & 63;
    if (v >= N) return;
    int s = start[v];
    int e = s + cnt[v];
    float dv = dinv[v];
    float acc = 0.0f;
    int i = s;
    for (; i + 3 < e; i += 4) {
        int   r0 = csr_src[i],     r1 = csr_src[i + 1];
        int   r2 = csr_src[i + 2], r3 = csr_src[i + 3];
        float w0 = dinv[r0], w1 = dinv[r1];
        float w2 = dinv[r2], w3 = dinv[r3];
        float v0 = hin[(size_t)r0 * DD + lane];
        float v1 = hin[(size_t)r1 * DD + lane];
        float v2 = hin[(size_t)r2 * DD + lane];
        float v3 = hin[(size_t)r3 * DD + lane];
        acc = fmaf(w0, v0, acc); acc = fmaf(w1, v1, acc);
        acc = fmaf(w2, v2, acc); acc = fmaf(w3, v3, acc);
    }
    for (; i < e; ++i) {
        int r = csr_src[i];
        acc = fmaf(dinv[r], hin[(size_t)r * DD + lane], acc);
    }
    hout[(size_t)v * DD + lane] = dv * acc;
}

// ---------------------------------------------------------------------------
extern "C" void kernel_launch(void* const* d_in, const int* in_sizes, int n_in,
                              void* d_out, int out_size, void* d_ws, size_t ws_size,
                              hipStream_t stream)
{
    const float* x     = (const float*)d_in[0];
    const int*   ei    = (const int*)  d_in[1];
    const float* W1    = (const float*)d_in[2];
    const float* b1    = (const float*)d_in[3];
    const float* gamma = (const float*)d_in[4];
    const float* beta  = (const float*)d_in[5];
    const float* W2    = (const float*)d_in[6];
    const float* b2    = (const float*)d_in[7];
    float* out = (float*)d_out;

    const int N = in_sizes[0] / F_IN;       // 100000
    const int M = in_sizes[1] / 2;          // 3300000
    const int* erow = ei;
    const int* ecol = ei + M;

    // workspace layout
    char* w = (char*)d_ws;
    int*   cnt     = (int*)w;   w += (size_t)N * 4;
    int*   cursor  = (int*)w;   w += (size_t)N * 4;
    int*   gctr    = (int*)w;   w += 16;
    int*   startv  = (int*)w;   w += (size_t)N * 4;
    float* dinv    = (float*)w; w += (size_t)N * 4;
    int*   csr_src = (int*)w;

    zero_k<<<512, 256, 0, stream>>>((int*)d_ws, 2 * N + 4);

    encoder_k<<<(N + RB - 1) / RB, 256, 0, stream>>>(x, W1, b1, gamma, beta, W2, b2, out, N);

    count_part_k<<<2048, 256, 0, stream>>>(ecol, M, cnt, N);
    scan_dinv_k<<<(N + 255) / 256, 256, 0, stream>>>(cnt, startv, dinv, gctr, N);
    fill_part_k<<<2048, 256, 0, stream>>>(erow, ecol, M, startv, cursor, csr_src, N);

    float* h0 = out;
    float* h1 = out + (size_t)N * DD;
    float* h2 = out + 2 * (size_t)N * DD;
    prop_k<<<(N + 3) / 4, 256, 0, stream>>>(h0, h1, startv, cnt, csr_src, dinv, N);
    prop_k<<<(N + 3) / 4, 256, 0, stream>>>(h1, h2, startv, cnt, csr_src, dinv, N);
}

// Round 4
// 710.870 us; speedup vs baseline: 1.6719x; 1.0262x over previous
//
#include <hip/hip_runtime.h>

#define F_IN 500
#define HH 32
#define DD 64
#define LN_EPS 1e-6f
#define RB 64           // rows per encoder block = threads per block (1 wave)
#define NCHUNK 16       // 15 full chunks of 32 k + tail of 20
#define NPART 8         // XCD partitions for count/fill scatter locality

typedef float4 f4;

__device__ __forceinline__ void gload_lds16(const void* g, void* l) {
    __builtin_amdgcn_global_load_lds((const __attribute__((address_space(1))) void*)g,
                                     (__attribute__((address_space(3))) void*)l, 16, 0, 0);
}

// ---------------------------------------------------------------------------
// Encoder: 1 wave / 64 rows per block; thread t owns row row0+t.
// x chunk (32 k-floats/row) + W1 slice (32x32) triple-buffered in LDS,
// counted vmcnt(12) pipeline, no barriers. W1/W2 read as LDS broadcasts.
// x LDS layout: slot n=r*8+u holds quad u^(r&7) of row r (bank-conflict-free).
// ---------------------------------------------------------------------------
__global__ __launch_bounds__(64)
void encoder_k(const float* __restrict__ x,
               const float* __restrict__ W1, const float* __restrict__ b1,
               const float* __restrict__ gamma, const float* __restrict__ beta,
               const float* __restrict__ W2, const float* __restrict__ b2,
               float* __restrict__ h0, int N)
{
    __shared__ f4 xs[3 * 512];      // 3 x 8 KB x-chunks
    __shared__ f4 w1s[3 * 256];     // 3 x 4 KB W1 slices (also reused for W2)

    const int t = threadIdx.x;      // 0..63
    const int row0 = blockIdx.x * RB;

    float acc[HH];
    #pragma unroll
    for (int j = 0; j < HH; ++j) acc[j] = b1[j];   // uniform -> s_load

    // stage chunk c into buf b: 8 x-loads (8 rows per instr, swizzled source)
    // + 4 W1-loads (contiguous 1KB each). 12 vmem ops total.
    #define STAGE_ALL(c_, b_) do {                                           \
        const int k0_ = (c_) * 32;                                           \
        f4* xd_ = &xs[(b_) * 512];                                           \
        const int g_ = (t & 7) ^ (t >> 3);                                   \
        _Pragma("unroll")                                                    \
        for (int i_ = 0; i_ < 8; ++i_) {                                     \
            int r_ = i_ * 8 + (t >> 3);                                      \
            int k_ = k0_ + 4 * g_;                                           \
            if (k_ >= F_IN) k_ = k0_;                                        \
            int row_ = row0 + r_; if (row_ >= N) row_ = N - 1;               \
            gload_lds16((const void*)(x + (size_t)row_ * F_IN + k_),         \
                        (void*)(xd_ + i_ * 64));                             \
        }                                                                    \
        f4* wd_ = &w1s[(b_) * 256];                                          \
        _Pragma("unroll")                                                    \
        for (int i_ = 0; i_ < 4; ++i_) {                                     \
            int off_ = k0_ * HH + i_ * 256 + t * 4;                          \
            if (off_ + 4 > F_IN * HH) off_ = 0;                              \
            gload_lds16((const void*)(W1 + off_), (void*)(wd_ + i_ * 64));   \
        }                                                                    \
    } while (0)

    // drain any stray vmem so hand-counted vmcnt is exact from here on
    asm volatile("s_waitcnt vmcnt(0)" ::: "memory");
    __builtin_amdgcn_sched_barrier(0);

    STAGE_ALL(0, 0);
    STAGE_ALL(1, 1);

    const int sw = t & 7;
    #pragma unroll 1
    for (int c = 0; c < NCHUNK; ++c) {
        if (c < NCHUNK - 1) {
            asm volatile("s_waitcnt vmcnt(12)" ::: "memory");   // chunk c landed
        } else {
            asm volatile("s_waitcnt vmcnt(0)" ::: "memory");    // last chunk + W2
        }
        __builtin_amdgcn_sched_barrier(0);
        if (c + 2 < NCHUNK) {
            STAGE_ALL(c + 2, (c + 2) % 3);
        }
        const f4* xb  = &xs[(c % 3) * 512 + t * 8];
        const f4* w1b = &w1s[(c % 3) * 256];
        const int nq = (c == NCHUNK - 1) ? 5 : 8;
        #pragma unroll
        for (int q = 0; q < 8; ++q) {
            if (q < nq) {
                f4 xv = xb[q ^ sw];
                #pragma unroll
                for (int dk = 0; dk < 4; ++dk) {
                    float xk = ((const float*)&xv)[dk];
                    const f4* wv = w1b + (q * 4 + dk) * 8;   // uniform -> broadcast
                    #pragma unroll
                    for (int jj = 0; jj < 8; ++jj) {
                        f4 wq = wv[jj];
                        acc[jj * 4 + 0] = fmaf(xk, wq.x, acc[jj * 4 + 0]);
                        acc[jj * 4 + 1] = fmaf(xk, wq.y, acc[jj * 4 + 1]);
                        acc[jj * 4 + 2] = fmaf(xk, wq.z, acc[jj * 4 + 2]);
                        acc[jj * 4 + 3] = fmaf(xk, wq.w, acc[jj * 4 + 3]);
                    }
                }
            }
        }
        if (c == NCHUNK - 2) {
            // stage W2 (8 KB) into w1s bufs 1..2 (both consumed). ds_reads of
            // this chunk must complete before the overwrite can land.
            asm volatile("s_waitcnt lgkmcnt(0)" ::: "memory");
            __builtin_amdgcn_sched_barrier(0);
            #pragma unroll
            for (int i_ = 0; i_ < 8; ++i_) {
                gload_lds16((const void*)(W2 + i_ * 256 + t * 4),
                            (void*)(&w1s[256] + i_ * 64));
            }
        }
    }
    #undef STAGE_ALL

    // ---- LayerNorm + relu (fully per-thread) ----
    float s = 0.f;
    #pragma unroll
    for (int j = 0; j < HH; ++j) s += acc[j];
    float mu = s * (1.0f / 32.0f);
    float var = 0.f;
    #pragma unroll
    for (int j = 0; j < HH; ++j) { float d = acc[j] - mu; var = fmaf(d, d, var); }
    float is = rsqrtf(var * (1.0f / 32.0f) + LN_EPS);
    #pragma unroll
    for (int j = 0; j < HH; ++j) {
        float hn = (acc[j] - mu) * is;
        hn = fmaf(hn, gamma[j], beta[j]);
        acc[j] = fmaxf(hn, 0.0f);
    }

    // ---- GEMM2: o[64] = relu(h) @ W2 + b2 (W2 broadcast from LDS) ----
    const f4* w2b = &w1s[256];      // [32 j][16 f4-of-d]
    float o[DD];
    #pragma unroll
    for (int d = 0; d < DD; ++d) o[d] = b2[d];
    #pragma unroll
    for (int j = 0; j < HH; ++j) {
        float hj = acc[j];
        #pragma unroll
        for (int dq = 0; dq < 16; ++dq) {
            f4 wq = w2b[j * 16 + dq];
            o[dq * 4 + 0] = fmaf(hj, wq.x, o[dq * 4 + 0]);
            o[dq * 4 + 1] = fmaf(hj, wq.y, o[dq * 4 + 1]);
            o[dq * 4 + 2] = fmaf(hj, wq.z, o[dq * 4 + 2]);
            o[dq * 4 + 3] = fmaf(hj, wq.w, o[dq * 4 + 3]);
        }
    }

    // ---- row L2 normalize ----
    float ss = 0.f;
    #pragma unroll
    for (int d = 0; d < DD; ++d) ss = fmaf(o[d], o[d], ss);
    float sc = 1.0f / fmaxf(sqrtf(ss), 1e-12f);

    // ---- transpose through xs (swizzled both phases) -> coalesced stores ----
    f4* tb = xs;                    // 1024 f4 = 16 KB
    #pragma unroll
    for (int dq = 0; dq < 16; ++dq) {
        f4 v4;
        v4.x = o[dq * 4 + 0] * sc; v4.y = o[dq * 4 + 1] * sc;
        v4.z = o[dq * 4 + 2] * sc; v4.w = o[dq * 4 + 3] * sc;
        tb[t * 16 + (dq ^ (t & 7))] = v4;
    }
    asm volatile("s_waitcnt lgkmcnt(0)" ::: "memory");
    __builtin_amdgcn_sched_barrier(0);
    const size_t lim = (size_t)N * 16;
    f4* out4 = (f4*)h0;
    #pragma unroll
    for (int i = 0; i < 16; ++i) {
        int gi = i * 64 + t;
        int r = gi >> 4, u = gi & 15;
        f4 v = tb[r * 16 + (u ^ (r & 7))];
        size_t go = (size_t)row0 * 16 + gi;
        if (go < lim) out4[go] = v;
    }
}

// ---------------------------------------------------------------------------
// Graph plumbing, XCD-partitioned (round-3, measured good).
// ---------------------------------------------------------------------------
__global__ void zero_k(int* __restrict__ p, int n)
{
    int i = blockIdx.x * blockDim.x + threadIdx.x;
    int stride = gridDim.x * blockDim.x;
    for (; i < n; i += stride) p[i] = 0;
}

__global__ __launch_bounds__(256)
void count_part_k(const int* __restrict__ col, int M, int* __restrict__ cnt, int N)
{
    const int part  = blockIdx.x & (NPART - 1);
    const int crank = blockIdx.x >> 3;
    const int cblocks = gridDim.x >> 3;
    const int nlo = (int)((long long)part * N / NPART);
    const int nhi = (int)((long long)(part + 1) * N / NPART);
    const int stride = cblocks * 256;
    for (int i = crank * 256 + threadIdx.x; i < M; i += stride) {
        int c = col[i];
        if (c >= nlo && c < nhi) atomicAdd(&cnt[c], 1);
    }
}

__global__ __launch_bounds__(256)
void scan_dinv_k(const int* __restrict__ cnt, int* __restrict__ start,
                 float* __restrict__ dinv, int* __restrict__ gctr, int N)
{
    __shared__ int sd[256];
    __shared__ int sbase;
    int t = threadIdx.x;
    int v = blockIdx.x * 256 + t;
    int c = (v < N) ? cnt[v] : 0;
    sd[t] = c;
    __syncthreads();
    #pragma unroll
    for (int off = 1; off < 256; off <<= 1) {
        int tmp = (t >= off) ? sd[t - off] : 0;
        __syncthreads();
        sd[t] += tmp;
        __syncthreads();
    }
    int incl = sd[t];
    if (t == 255) sbase = atomicAdd(gctr, sd[255]);
    __syncthreads();
    if (v < N) {
        start[v] = sbase + incl - c;
        dinv[v]  = (c > 0) ? rsqrtf((float)c) : 0.0f;
    }
}

__global__ __launch_bounds__(256)
void fill_part_k(const int* __restrict__ row, const int* __restrict__ col, int M,
                 const int* __restrict__ start, int* __restrict__ cursor,
                 int* __restrict__ csr_src, int N)
{
    const int part  = blockIdx.x & (NPART - 1);
    const int crank = blockIdx.x >> 3;
    const int cblocks = gridDim.x >> 3;
    const int nlo = (int)((long long)part * N / NPART);
    const int nhi = (int)((long long)(part + 1) * N / NPART);
    const int stride = cblocks * 256;
    for (int i = crank * 256 + threadIdx.x; i < M; i += stride) {
        int c = col[i];
        if (c >= nlo && c < nhi) {
            int r = row[i];
            int pos = start[c] + atomicAdd(&cursor[c], 1);
            csr_src[pos] = r;
        }
    }
}

// ---------------------------------------------------------------------------
// Propagation: wave per node, lane = feature dim.
// hout[v] = dinv[v] * sum_r dinv[r]*hin[r]
// ---------------------------------------------------------------------------
__global__ __launch_bounds__(256)
void prop_k(const float* __restrict__ hin, float* __restrict__ hout,
            const int* __restrict__ start, const int* __restrict__ cnt,
            const int* __restrict__ csr_src, const float* __restrict__ dinv, int N)
{
    int v = blockIdx.x * 4 + (threadIdx.x >> 6);
    int lane = threadIdx.x & 63;
    if (v >= N) return;
    int s = start[v];
    int e = s + cnt[v];
    float dv = dinv[v];
    float acc = 0.0f;
    int i = s;
    for (; i + 3 < e; i += 4) {
        int   r0 = csr_src[i],     r1 = csr_src[i + 1];
        int   r2 = csr_src[i + 2], r3 = csr_src[i + 3];
        float w0 = dinv[r0], w1 = dinv[r1];
        float w2 = dinv[r2], w3 = dinv[r3];
        float v0 = hin[(size_t)r0 * DD + lane];
        float v1 = hin[(size_t)r1 * DD + lane];
        float v2 = hin[(size_t)r2 * DD + lane];
        float v3 = hin[(size_t)r3 * DD + lane];
        acc = fmaf(w0, v0, acc); acc = fmaf(w1, v1, acc);
        acc = fmaf(w2, v2, acc); acc = fmaf(w3, v3, acc);
    }
    for (; i < e; ++i) {
        int r = csr_src[i];
        acc = fmaf(dinv[r], hin[(size_t)r * DD + lane], acc);
    }
    hout[(size_t)v * DD + lane] = dv * acc;
}

// ---------------------------------------------------------------------------
extern "C" void kernel_launch(void* const* d_in, const int* in_sizes, int n_in,
                              void* d_out, int out_size, void* d_ws, size_t ws_size,
                              hipStream_t stream)
{
    const float* x     = (const float*)d_in[0];
    const int*   ei    = (const int*)  d_in[1];
    const float* W1    = (const float*)d_in[2];
    const float* b1    = (const float*)d_in[3];
    const float* gamma = (const float*)d_in[4];
    const float* beta  = (const float*)d_in[5];
    const float* W2    = (const float*)d_in[6];
    const float* b2    = (const float*)d_in[7];
    float* out = (float*)d_out;

    const int N = in_sizes[0] / F_IN;       // 100000
    const int M = in_sizes[1] / 2;          // 3300000
    const int* erow = ei;
    const int* ecol = ei + M;

    // workspace layout
    char* w = (char*)d_ws;
    int*   cnt     = (int*)w;   w += (size_t)N * 4;
    int*   cursor  = (int*)w;   w += (size_t)N * 4;
    int*   gctr    = (int*)w;   w += 16;
    int*   startv  = (int*)w;   w += (size_t)N * 4;
    float* dinv    = (float*)w; w += (size_t)N * 4;
    int*   csr_src = (int*)w;

    zero_k<<<512, 256, 0, stream>>>((int*)d_ws, 2 * N + 4);

    encoder_k<<<(N + RB - 1) / RB, 64, 0, stream>>>(x, W1, b1, gamma, beta, W2, b2, out, N);

    count_part_k<<<2048, 256, 0, stream>>>(ecol, M, cnt, N);
    scan_dinv_k<<<(N + 255) / 256, 256, 0, stream>>>(cnt, startv, dinv, gctr, N);
    fill_part_k<<<2048, 256, 0, stream>>>(erow, ecol, M, startv, cursor, csr_src, N);

    float* h0 = out;
    float* h1 = out + (size_t)N * DD;
    float* h2 = out + 2 * (size_t)N * DD;
    prop_k<<<(N + 3) / 4, 256, 0, stream>>>(h0, h1, startv, cnt, csr_src, dinv, N);
    prop_k<<<(N + 3) / 4, 256, 0, stream>>>(h1, h2, startv, cnt, csr_src, dinv, N);
}

// Round 5
// 611.755 us; speedup vs baseline: 1.9427x; 1.1620x over previous
//
#include <hip/hip_runtime.h>

#define F_IN 500
#define HH 32
#define DD 64
#define LN_EPS 1e-6f
#define NPART 8

typedef float4 f4;
typedef _Float16 h16;

__device__ __forceinline__ void gload_lds16(const void* g, void* l) {
    __builtin_amdgcn_global_load_lds((const __attribute__((address_space(1))) void*)g,
                                     (__attribute__((address_space(3))) void*)l, 16, 0, 0);
}

// ---------------------------------------------------------------------------
// Encoder v3: block = 256 thr (4 waves), 64 rows. Thread = (row r = l>>2,
// j-quarter jq = l&3): acc[8] over full K -> no GEMM1 cross-thread combine.
// 6250 waves total (6.1/SIMD) -> latency hidden by TLP.
// LDS: per-wave x dbuf (swizzled slots) + shared W1 dbuf + W2. 32 KB/block.
// ---------------------------------------------------------------------------
__global__ __launch_bounds__(256, 4)
void encoder_k(const float* __restrict__ x,
               const float* __restrict__ W1, const float* __restrict__ b1,
               const float* __restrict__ gamma, const float* __restrict__ beta,
               const float* __restrict__ W2, const float* __restrict__ b2,
               float* __restrict__ h0, int N)
{
    __shared__ f4 xsw[4][2][128];   // per-wave x chunk dbuf: slot r*8+u holds quad u^(r&7)
    __shared__ f4 w1s[2][256];      // shared W1 chunk dbuf [k'(32)][j(32)] linear
    __shared__ f4 w2s[512];         // W2 [32 j][64 d] linear

    const int t = threadIdx.x;
    const int w = t >> 6;
    const int l = t & 63;
    const int r = l >> 2;           // row within wave (0..15)
    const int jq = l & 3;           // j-quarter (8 channels)
    const int rowBlock = blockIdx.x * 64;
    const int gr = rowBlock + w * 16 + r;

    // per-lane parameter registers
    f4 b1lo = *(const f4*)(b1 + jq * 8);
    f4 b1hi = *(const f4*)(b1 + jq * 8 + 4);
    f4 galo = *(const f4*)(gamma + jq * 8);
    f4 gahi = *(const f4*)(gamma + jq * 8 + 4);
    f4 belo = *(const f4*)(beta + jq * 8);
    f4 behi = *(const f4*)(beta + jq * 8 + 4);

    // stage W2 once (8 instrs across 4 waves)
    #pragma unroll
    for (int i = 0; i < 2; ++i)
        gload_lds16((const void*)(W2 + ((size_t)(i * 4 + w) * 64 + l) * 4),
                    (void*)&w2s[(i * 4 + w) * 64]);

    #define STAGE_X(c_, pb_) do {                                            \
        const int k0_ = (c_) * 32;                                           \
        _Pragma("unroll")                                                    \
        for (int i_ = 0; i_ < 2; ++i_) {                                     \
            int n_ = i_ * 64 + l;                                            \
            int rr_ = n_ >> 3, u_ = n_ & 7;                                  \
            int g_ = u_ ^ (rr_ & 7);                                         \
            int k_ = k0_ + 4 * g_; if (k_ >= F_IN) k_ = k0_;                 \
            int row_ = rowBlock + w * 16 + rr_; if (row_ >= N) row_ = N - 1; \
            gload_lds16((const void*)(x + (size_t)row_ * F_IN + k_),         \
                        (void*)&xsw[w][pb_][i_ * 64]);                       \
        } } while (0)

    #define STAGE_W1(c_, pb_) do {                                           \
        int off_ = (c_) * 1024 + w * 256 + l * 4;                            \
        if (off_ + 4 > F_IN * HH) off_ = 0;                                  \
        gload_lds16((const void*)(W1 + off_), (void*)&w1s[pb_][w * 64]);     \
    } while (0)

    STAGE_X(0, 0); STAGE_W1(0, 0);

    float acc[8] = {b1lo.x, b1lo.y, b1lo.z, b1lo.w, b1hi.x, b1hi.y, b1hi.z, b1hi.w};

    __syncthreads();                // chunk0 + W2 landed

    #pragma unroll 1
    for (int c = 0; c < 16; ++c) {
        const int pb = c & 1;
        if (c < 15) { STAGE_X(c + 1, pb ^ 1); STAGE_W1(c + 1, pb ^ 1); }
        f4 xr[8];
        #pragma unroll
        for (int q = 0; q < 8; ++q) xr[q] = xsw[w][pb][r * 8 + (q ^ (r & 7))];
        const int nq = (c == 15) ? 5 : 8;
        #pragma unroll
        for (int q = 0; q < 8; ++q) {
            if (q < nq) {
                #pragma unroll
                for (int dk = 0; dk < 4; ++dk) {
                    float xk = ((const float*)&xr[q])[dk];
                    f4 wa = w1s[pb][(q * 4 + dk) * 8 + jq * 2];
                    f4 wb = w1s[pb][(q * 4 + dk) * 8 + jq * 2 + 1];
                    acc[0] = fmaf(xk, wa.x, acc[0]);
                    acc[1] = fmaf(xk, wa.y, acc[1]);
                    acc[2] = fmaf(xk, wa.z, acc[2]);
                    acc[3] = fmaf(xk, wa.w, acc[3]);
                    acc[4] = fmaf(xk, wb.x, acc[4]);
                    acc[5] = fmaf(xk, wb.y, acc[5]);
                    acc[6] = fmaf(xk, wb.z, acc[6]);
                    acc[7] = fmaf(xk, wb.w, acc[7]);
                }
            }
        }
        __syncthreads();
    }
    #undef STAGE_X
    #undef STAGE_W1

    // ---- LayerNorm over 32 j: 4-lane group reduce (lanes share row) ----
    float s = 0.f;
    #pragma unroll
    for (int j = 0; j < 8; ++j) s += acc[j];
    s += __shfl_xor(s, 1); s += __shfl_xor(s, 2);
    float mu = s * (1.0f / 32.0f);
    float var = 0.f;
    #pragma unroll
    for (int j = 0; j < 8; ++j) { float d = acc[j] - mu; var = fmaf(d, d, var); }
    var += __shfl_xor(var, 1); var += __shfl_xor(var, 2);
    float is = rsqrtf(var * (1.0f / 32.0f) + LN_EPS);
    const float* gp = (const float*)&galo;
    const float* bp = (const float*)&belo;
    #pragma unroll
    for (int j = 0; j < 8; ++j) {
        float g = (j < 4) ? ((const float*)&galo)[j] : ((const float*)&gahi)[j - 4];
        float b = (j < 4) ? ((const float*)&belo)[j] : ((const float*)&behi)[j - 4];
        float hn = fmaf((acc[j] - mu) * is, g, b);
        acc[j] = fmaxf(hn, 0.0f);
    }
    (void)gp; (void)bp;

    // ---- h -> per-wave LDS (swizzled), then each lane reads its full row ----
    f4* hb = &xsw[w][0][0];
    f4 hv0; hv0.x = acc[0]; hv0.y = acc[1]; hv0.z = acc[2]; hv0.w = acc[3];
    f4 hv1; hv1.x = acc[4]; hv1.y = acc[5]; hv1.z = acc[6]; hv1.w = acc[7];
    hb[r * 8 + ((jq * 2) ^ (r & 7))] = hv0;
    hb[r * 8 + ((jq * 2 + 1) ^ (r & 7))] = hv1;
    asm volatile("s_waitcnt lgkmcnt(0)" ::: "memory");
    __builtin_amdgcn_sched_barrier(0);
    f4 hr[8];
    #pragma unroll
    for (int q = 0; q < 8; ++q) hr[q] = hb[r * 8 + (q ^ (r & 7))];

    // ---- GEMM2: lane (r, dq=jq) computes o[16] = h[r][:] @ W2[:, dq*16..] ----
    float o[16];
    #pragma unroll
    for (int s4 = 0; s4 < 4; ++s4) {
        f4 bv = *(const f4*)(b2 + jq * 16 + s4 * 4);
        o[s4 * 4 + 0] = bv.x; o[s4 * 4 + 1] = bv.y;
        o[s4 * 4 + 2] = bv.z; o[s4 * 4 + 3] = bv.w;
    }
    #pragma unroll
    for (int q = 0; q < 8; ++q) {
        #pragma unroll
        for (int dk = 0; dk < 4; ++dk) {
            float hj = ((const float*)&hr[q])[dk];
            int j = q * 4 + dk;
            #pragma unroll
            for (int s4 = 0; s4 < 4; ++s4) {
                f4 wv = w2s[j * 16 + jq * 4 + s4];
                o[s4 * 4 + 0] = fmaf(hj, wv.x, o[s4 * 4 + 0]);
                o[s4 * 4 + 1] = fmaf(hj, wv.y, o[s4 * 4 + 1]);
                o[s4 * 4 + 2] = fmaf(hj, wv.z, o[s4 * 4 + 2]);
                o[s4 * 4 + 3] = fmaf(hj, wv.w, o[s4 * 4 + 3]);
            }
        }
    }

    // ---- row L2 normalize (4-lane group) + store 64B/lane ----
    float ss = 0.f;
    #pragma unroll
    for (int d = 0; d < 16; ++d) ss = fmaf(o[d], o[d], ss);
    ss += __shfl_xor(ss, 1); ss += __shfl_xor(ss, 2);
    float sc = 1.0f / fmaxf(sqrtf(ss), 1e-12f);
    if (gr < N) {
        f4* outp = (f4*)(h0 + (size_t)gr * DD + jq * 16);
        #pragma unroll
        for (int s4 = 0; s4 < 4; ++s4) {
            f4 v; v.x = o[s4 * 4 + 0] * sc; v.y = o[s4 * 4 + 1] * sc;
            v.z = o[s4 * 4 + 2] * sc; v.w = o[s4 * 4 + 3] * sc;
            outp[s4] = v;
        }
    }
}

// ---------------------------------------------------------------------------
// Graph plumbing (round-3, measured good)
// ---------------------------------------------------------------------------
__global__ void zero_k(int* __restrict__ p, int n)
{
    int i = blockIdx.x * blockDim.x + threadIdx.x;
    int stride = gridDim.x * blockDim.x;
    for (; i < n; i += stride) p[i] = 0;
}

__global__ __launch_bounds__(256)
void count_part_k(const int* __restrict__ col, int M, int* __restrict__ cnt, int N)
{
    const int part  = blockIdx.x & (NPART - 1);
    const int crank = blockIdx.x >> 3;
    const int cblocks = gridDim.x >> 3;
    const int nlo = (int)((long long)part * N / NPART);
    const int nhi = (int)((long long)(part + 1) * N / NPART);
    const int stride = cblocks * 256;
    for (int i = crank * 256 + threadIdx.x; i < M; i += stride) {
        int c = col[i];
        if (c >= nlo && c < nhi) atomicAdd(&cnt[c], 1);
    }
}

__global__ __launch_bounds__(256)
void scan_dinv_k(const int* __restrict__ cnt, int* __restrict__ start,
                 float* __restrict__ dinv, int* __restrict__ gctr, int N)
{
    __shared__ int sd[256];
    __shared__ int sbase;
    int t = threadIdx.x;
    int v = blockIdx.x * 256 + t;
    int c = (v < N) ? cnt[v] : 0;
    sd[t] = c;
    __syncthreads();
    #pragma unroll
    for (int off = 1; off < 256; off <<= 1) {
        int tmp = (t >= off) ? sd[t - off] : 0;
        __syncthreads();
        sd[t] += tmp;
        __syncthreads();
    }
    int incl = sd[t];
    if (t == 255) sbase = atomicAdd(gctr, sd[255]);
    __syncthreads();
    if (v < N) {
        start[v] = sbase + incl - c;
        dinv[v]  = (c > 0) ? rsqrtf((float)c) : 0.0f;
    }
}

__global__ __launch_bounds__(256)
void fill_part_k(const int* __restrict__ row, const int* __restrict__ col, int M,
                 const int* __restrict__ start, int* __restrict__ cursor,
                 int* __restrict__ csr_src, int N)
{
    const int part  = blockIdx.x & (NPART - 1);
    const int crank = blockIdx.x >> 3;
    const int cblocks = gridDim.x >> 3;
    const int nlo = (int)((long long)part * N / NPART);
    const int nhi = (int)((long long)(part + 1) * N / NPART);
    const int stride = cblocks * 256;
    for (int i = crank * 256 + threadIdx.x; i < M; i += stride) {
        int c = col[i];
        if (c >= nlo && c < nhi) {
            int r = row[i];
            int pos = start[c] + atomicAdd(&cursor[c], 1);
            csr_src[pos] = r;
        }
    }
}

// ---------------------------------------------------------------------------
// mirror[v][d] = dinv[v] * h[v][d]  as fp16 (gather table for prop)
// ---------------------------------------------------------------------------
__global__ __launch_bounds__(256)
void mkmir_k(const float* __restrict__ h, const float* __restrict__ dinv,
             h16* __restrict__ m, int N)
{
    int i = blockIdx.x * 256 + threadIdx.x;     // one float2 (2 dims)
    if (i >= N * 32) return;
    float2 v = ((const float2*)h)[i];
    float dv = dinv[i >> 5];
    h16 a = (h16)(v.x * dv);
    h16 b = (h16)(v.y * dv);
    unsigned short ua = *(unsigned short*)&a;
    unsigned short ub = *(unsigned short*)&b;
    ((unsigned int*)m)[i] = (unsigned)ua | ((unsigned)ub << 16);
}

// ---------------------------------------------------------------------------
// Propagation on fp16 pre-scaled mirror: hout[v] = dinv[v] * sum_r mirror[r]
// mout (next-step mirror) = dinv[v] * hout[v]; null on last step.
// ---------------------------------------------------------------------------
__global__ __launch_bounds__(256)
void prop16_k(const h16* __restrict__ min_, float* __restrict__ hout,
              h16* __restrict__ mout,
              const int* __restrict__ start, const int* __restrict__ cnt,
              const int* __restrict__ csr_src, const float* __restrict__ dinv, int N)
{
    int v = blockIdx.x * 4 + (threadIdx.x >> 6);
    int lane = threadIdx.x & 63;
    if (v >= N) return;
    int s = start[v];
    int e = s + cnt[v];
    float dv = dinv[v];
    float acc = 0.0f;
    int i = s;
    for (; i + 3 < e; i += 4) {
        int r0 = csr_src[i],     r1 = csr_src[i + 1];
        int r2 = csr_src[i + 2], r3 = csr_src[i + 3];
        float v0 = (float)min_[(size_t)r0 * DD + lane];
        float v1 = (float)min_[(size_t)r1 * DD + lane];
        float v2 = (float)min_[(size_t)r2 * DD + lane];
        float v3 = (float)min_[(size_t)r3 * DD + lane];
        acc += v0 + v1 + v2 + v3;
    }
    for (; i < e; ++i) {
        int r = csr_src[i];
        acc += (float)min_[(size_t)r * DD + lane];
    }
    float res = dv * acc;
    hout[(size_t)v * DD + lane] = res;
    if (mout) mout[(size_t)v * DD + lane] = (h16)(dv * res);
}

// ---------------------------------------------------------------------------
extern "C" void kernel_launch(void* const* d_in, const int* in_sizes, int n_in,
                              void* d_out, int out_size, void* d_ws, size_t ws_size,
                              hipStream_t stream)
{
    const float* x     = (const float*)d_in[0];
    const int*   ei    = (const int*)  d_in[1];
    const float* W1    = (const float*)d_in[2];
    const float* b1    = (const float*)d_in[3];
    const float* gamma = (const float*)d_in[4];
    const float* beta  = (const float*)d_in[5];
    const float* W2    = (const float*)d_in[6];
    const float* b2    = (const float*)d_in[7];
    float* out = (float*)d_out;

    const int N = in_sizes[0] / F_IN;       // 100000
    const int M = in_sizes[1] / 2;          // 3300000
    const int* erow = ei;
    const int* ecol = ei + M;

    // workspace layout
    char* w = (char*)d_ws;
    int*   cnt     = (int*)w;   w += (size_t)N * 4;
    int*   cursor  = (int*)w;   w += (size_t)N * 4;
    int*   gctr    = (int*)w;   w += 16;
    int*   startv  = (int*)w;   w += (size_t)N * 4;
    float* dinv    = (float*)w; w += (size_t)N * 4;
    int*   csr_src = (int*)w;   w += (size_t)M * 4;
    h16*   mir0    = (h16*)w;   w += (size_t)N * DD * 2;
    h16*   mir1    = (h16*)w;

    zero_k<<<512, 256, 0, stream>>>((int*)d_ws, 2 * N + 4);

    encoder_k<<<(N + 63) / 64, 256, 0, stream>>>(x, W1, b1, gamma, beta, W2, b2, out, N);

    count_part_k<<<2048, 256, 0, stream>>>(ecol, M, cnt, N);
    scan_dinv_k<<<(N + 255) / 256, 256, 0, stream>>>(cnt, startv, dinv, gctr, N);
    fill_part_k<<<2048, 256, 0, stream>>>(erow, ecol, M, startv, cursor, csr_src, N);

    float* h0 = out;
    float* h1 = out + (size_t)N * DD;
    float* h2 = out + 2 * (size_t)N * DD;

    mkmir_k<<<(N * 32 + 255) / 256, 256, 0, stream>>>(h0, dinv, mir0, N);
    prop16_k<<<(N + 3) / 4, 256, 0, stream>>>(mir0, h1, mir1, startv, cnt, csr_src, dinv, N);
    prop16_k<<<(N + 3) / 4, 256, 0, stream>>>(mir1, h2, (h16*)nullptr, startv, cnt, csr_src, dinv, N);
}